// Round 1
// baseline (3509.568 us; speedup 1.0000x reference)
//
#include <hip/hip_runtime.h>

// GIN 3-layer: out = (h + segment_sum(h[src], dst)) @ W + b per layer, ReLU on 1,2.
// N=100000 nodes, E=1.6M edges, dims 32 -> 64 -> 64 -> 10, fp32.

#define GIN_N 100000

// Scatter-add aggregation: one thread per (edge, 4-feature chunk).
// Consecutive threads of a wave cover consecutive float4s of the same source
// row -> coalesced gather; atomics land in L2-resident agg buffer.
template <int D>
__global__ void scatter_add_kernel(const float* __restrict__ feat,
                                   const int* __restrict__ src,
                                   const int* __restrict__ dst,
                                   float* __restrict__ agg, int E) {
    constexpr int C = D / 4;  // float4 chunks per row
    int tid = blockIdx.x * blockDim.x + threadIdx.x;
    int e = tid / C;
    int j = tid - e * C;
    if (e >= E) return;
    int s = src[e];
    int d = dst[e];
    float4 v = reinterpret_cast<const float4*>(feat)[(size_t)s * C + j];
    float* ad = agg + (size_t)d * D + 4 * j;
    atomicAdd(ad + 0, v.x);
    atomicAdd(ad + 1, v.y);
    atomicAdd(ad + 2, v.z);
    atomicAdd(ad + 3, v.w);
}

// Per-node MLP: out[n] = act((x[n] + agg[n]) @ W + b).
// W (K x M) and b staged in LDS; TPN threads cooperate per node, each
// computing MT = M/TPN output columns. LDS access is 2-way aliased at worst
// (free on gfx950 per bank-conflict measurements).
template <int K, int M, int TPN, bool RELU>
__global__ void node_mlp_kernel(const float* __restrict__ x,
                                const float* __restrict__ agg,
                                const float* __restrict__ W,
                                const float* __restrict__ b,
                                float* __restrict__ out, int N) {
    constexpr int MT = M / TPN;
    __shared__ float Ws[K * M];
    __shared__ float bs[M];
    for (int i = threadIdx.x; i < K * M; i += blockDim.x) Ws[i] = W[i];
    for (int i = threadIdx.x; i < M; i += blockDim.x) bs[i] = b[i];
    __syncthreads();

    int t = blockIdx.x * blockDim.x + threadIdx.x;
    int n = t / TPN;
    int sub = t - n * TPN;
    if (n >= N) return;

    float acc[MT];
#pragma unroll
    for (int jj = 0; jj < MT; ++jj) acc[jj] = bs[sub * MT + jj];

    const float4* xv = reinterpret_cast<const float4*>(x + (size_t)n * K);
    const float4* av = reinterpret_cast<const float4*>(agg + (size_t)n * K);
#pragma unroll
    for (int kc = 0; kc < K / 4; ++kc) {
        float4 xx = xv[kc];
        float4 aa = av[kc];
        float v0 = xx.x + aa.x;
        float v1 = xx.y + aa.y;
        float v2 = xx.z + aa.z;
        float v3 = xx.w + aa.w;
        const float* wr0 = &Ws[(kc * 4 + 0) * M + sub * MT];
        const float* wr1 = &Ws[(kc * 4 + 1) * M + sub * MT];
        const float* wr2 = &Ws[(kc * 4 + 2) * M + sub * MT];
        const float* wr3 = &Ws[(kc * 4 + 3) * M + sub * MT];
#pragma unroll
        for (int jj = 0; jj < MT; ++jj) {
            acc[jj] = fmaf(v0, wr0[jj], acc[jj]);
            acc[jj] = fmaf(v1, wr1[jj], acc[jj]);
            acc[jj] = fmaf(v2, wr2[jj], acc[jj]);
            acc[jj] = fmaf(v3, wr3[jj], acc[jj]);
        }
    }

    float* o = out + (size_t)n * M + sub * MT;
#pragma unroll
    for (int jj = 0; jj < MT; ++jj) {
        float r = acc[jj];
        o[jj] = RELU ? fmaxf(r, 0.0f) : r;
    }
}

extern "C" void kernel_launch(void* const* d_in, const int* in_sizes, int n_in,
                              void* d_out, int out_size, void* d_ws, size_t ws_size,
                              hipStream_t stream) {
    const float* x  = (const float*)d_in[0];
    const int*   ei = (const int*)d_in[1];
    const float* W1 = (const float*)d_in[2];
    const float* b1 = (const float*)d_in[3];
    const float* W2 = (const float*)d_in[4];
    const float* b2 = (const float*)d_in[5];
    const float* W3 = (const float*)d_in[6];
    const float* b3 = (const float*)d_in[7];
    float* out = (float*)d_out;

    const int N = GIN_N;
    const int E = in_sizes[1] / 2;   // edge_index is [2, E]
    const int* src = ei;
    const int* dst = ei + E;

    // Workspace layout (floats): agg G (N*64), h1 (N*64), h2 (N*64) = 76.8 MB
    float* G  = (float*)d_ws;
    float* B1 = G  + (size_t)N * 64;
    float* B2 = B1 + (size_t)N * 64;

    const int BLK = 256;

    // ---- Layer 1: d=32 -> 64, ReLU ----
    hipMemsetAsync(G, 0, (size_t)N * 32 * sizeof(float), stream);
    {
        long long threads = (long long)E * 8;
        scatter_add_kernel<32><<<(int)((threads + BLK - 1) / BLK), BLK, 0, stream>>>(
            x, src, dst, G, E);
        node_mlp_kernel<32, 64, 4, true><<<(N * 4 + BLK - 1) / BLK, BLK, 0, stream>>>(
            x, G, W1, b1, B1, N);
    }

    // ---- Layer 2: d=64 -> 64, ReLU ----
    hipMemsetAsync(G, 0, (size_t)N * 64 * sizeof(float), stream);
    {
        long long threads = (long long)E * 16;
        scatter_add_kernel<64><<<(int)((threads + BLK - 1) / BLK), BLK, 0, stream>>>(
            B1, src, dst, G, E);
        node_mlp_kernel<64, 64, 4, true><<<(N * 4 + BLK - 1) / BLK, BLK, 0, stream>>>(
            B1, G, W2, b2, B2, N);
    }

    // ---- Layer 3: d=64 -> 10, no activation ----
    hipMemsetAsync(G, 0, (size_t)N * 64 * sizeof(float), stream);
    {
        long long threads = (long long)E * 16;
        scatter_add_kernel<64><<<(int)((threads + BLK - 1) / BLK), BLK, 0, stream>>>(
            B2, src, dst, G, E);
        node_mlp_kernel<64, 10, 2, false><<<(N * 2 + BLK - 1) / BLK, BLK, 0, stream>>>(
            B2, G, W3, b3, out, N);
    }
}

// Round 2
// 389.839 us; speedup vs baseline: 9.0026x; 9.0026x over previous
//
#include <hip/hip_runtime.h>

// GIN 3-layer via ELL adjacency + gather-side reduction (no fp32 atomics).
// N=100000, E=1.6M, dims 32 -> 64 -> 64 -> 10, fp32.
// Layer 3 uses linearity: (h + A h) @ W3 + b3 == t + A t + b3 with t = h @ W3,
// so the last aggregation runs in 10-dim space.

#define GIN_N 100000
#define CAP 64   // max in-degree capacity (mean 16, ~35 max for random graph)

// Build ELL adjacency: deg[] must be zeroed first. One int atomic per edge.
__global__ void fill_adj_kernel(const int* __restrict__ src,
                                const int* __restrict__ dst,
                                int* __restrict__ deg,
                                int* __restrict__ adj, int E) {
    int e = blockIdx.x * blockDim.x + threadIdx.x;
    if (e >= E) return;
    int d = dst[e];
    int pos = atomicAdd(&deg[d], 1);
    if (pos < CAP) adj[(size_t)d * CAP + pos] = src[e];
}

// Gather-side aggregation: agg[n] = sum_{s in adj[n]} feat[s].
// TPN = D/4 threads per node, each owns one float4 chunk.
template <int D>
__global__ void gather_kernel(const float* __restrict__ feat,
                              const int* __restrict__ deg,
                              const int* __restrict__ adj,
                              float* __restrict__ agg, int N) {
    constexpr int TPN = D / 4;
    int t = blockIdx.x * blockDim.x + threadIdx.x;
    int n = t / TPN;
    int j = t - n * TPN;
    if (n >= GIN_N) return;
    int d = deg[n];
    const int* row = adj + (size_t)n * CAP;
    const float4* f4 = reinterpret_cast<const float4*>(feat);
    float4 acc = make_float4(0.f, 0.f, 0.f, 0.f);
    int k = 0;
    for (; k + 1 < d; k += 2) {
        int s0 = row[k];
        int s1 = row[k + 1];
        float4 v0 = f4[(size_t)s0 * TPN + j];
        float4 v1 = f4[(size_t)s1 * TPN + j];
        acc.x += v0.x + v1.x;
        acc.y += v0.y + v1.y;
        acc.z += v0.z + v1.z;
        acc.w += v0.w + v1.w;
    }
    if (k < d) {
        float4 v = f4[(size_t)row[k] * TPN + j];
        acc.x += v.x; acc.y += v.y; acc.z += v.z; acc.w += v.w;
    }
    reinterpret_cast<float4*>(agg)[(size_t)n * TPN + j] = acc;
}

// Final aggregation in 10-dim output space: out[n] = t[n] + sum t[adj[n]] + b3.
__global__ void gather_final_kernel(const float* __restrict__ tmat,
                                    const int* __restrict__ deg,
                                    const int* __restrict__ adj,
                                    const float* __restrict__ b3,
                                    float* __restrict__ out, int N) {
    int t = blockIdx.x * blockDim.x + threadIdx.x;
    int n = t >> 4;
    int j = t & 15;
    if (n >= GIN_N || j >= 10) return;
    int d = deg[n];
    const int* row = adj + (size_t)n * CAP;
    float acc = tmat[(size_t)n * 10 + j];
    for (int k = 0; k < d; ++k)
        acc += tmat[(size_t)row[k] * 10 + j];
    out[(size_t)n * 10 + j] = acc + b3[j];
}

// Per-node MLP: out[n] = act((x[n] [+ agg[n]]) @ W [+ b]).
// W (K x M) and bias staged in LDS; TPN threads per node, MT = M/TPN cols each.
// AGG=false -> computes x @ W only (used for layer-3 pre-aggregation t).
template <int K, int M, int TPN, bool RELU, bool BIAS, bool AGG>
__global__ void node_mlp_kernel(const float* __restrict__ x,
                                const float* __restrict__ agg,
                                const float* __restrict__ W,
                                const float* __restrict__ b,
                                float* __restrict__ out, int N) {
    constexpr int MT = M / TPN;
    __shared__ float Ws[K * M];
    __shared__ float bs[M];
    for (int i = threadIdx.x; i < K * M; i += blockDim.x) Ws[i] = W[i];
    if (BIAS)
        for (int i = threadIdx.x; i < M; i += blockDim.x) bs[i] = b[i];
    __syncthreads();

    int t = blockIdx.x * blockDim.x + threadIdx.x;
    int n = t / TPN;
    int sub = t - n * TPN;
    if (n >= GIN_N) return;

    float acc[MT];
#pragma unroll
    for (int jj = 0; jj < MT; ++jj) acc[jj] = BIAS ? bs[sub * MT + jj] : 0.0f;

    const float4* xv = reinterpret_cast<const float4*>(x + (size_t)n * K);
    const float4* av = reinterpret_cast<const float4*>(agg + (size_t)n * K);
#pragma unroll
    for (int kc = 0; kc < K / 4; ++kc) {
        float4 xx = xv[kc];
        float v0 = xx.x, v1 = xx.y, v2 = xx.z, v3 = xx.w;
        if (AGG) {
            float4 aa = av[kc];
            v0 += aa.x; v1 += aa.y; v2 += aa.z; v3 += aa.w;
        }
        const float* wr0 = &Ws[(kc * 4 + 0) * M + sub * MT];
        const float* wr1 = &Ws[(kc * 4 + 1) * M + sub * MT];
        const float* wr2 = &Ws[(kc * 4 + 2) * M + sub * MT];
        const float* wr3 = &Ws[(kc * 4 + 3) * M + sub * MT];
#pragma unroll
        for (int jj = 0; jj < MT; ++jj) {
            acc[jj] = fmaf(v0, wr0[jj], acc[jj]);
            acc[jj] = fmaf(v1, wr1[jj], acc[jj]);
            acc[jj] = fmaf(v2, wr2[jj], acc[jj]);
            acc[jj] = fmaf(v3, wr3[jj], acc[jj]);
        }
    }

    float* o = out + (size_t)n * M + sub * MT;
#pragma unroll
    for (int jj = 0; jj < MT; ++jj) {
        float r = acc[jj];
        o[jj] = RELU ? fmaxf(r, 0.0f) : r;
    }
}

extern "C" void kernel_launch(void* const* d_in, const int* in_sizes, int n_in,
                              void* d_out, int out_size, void* d_ws, size_t ws_size,
                              hipStream_t stream) {
    const float* x  = (const float*)d_in[0];
    const int*   ei = (const int*)d_in[1];
    const float* W1 = (const float*)d_in[2];
    const float* b1 = (const float*)d_in[3];
    const float* W2 = (const float*)d_in[4];
    const float* b2 = (const float*)d_in[5];
    const float* W3 = (const float*)d_in[6];
    const float* b3 = (const float*)d_in[7];
    float* out = (float*)d_out;

    const int N = GIN_N;
    const int E = in_sizes[1] / 2;   // edge_index is [2, E]
    const int* src = ei;
    const int* dst = ei + E;

    // Workspace layout:
    //   floats: G (N*64), H1 (N*64), H2 (N*64)  = 76.8 MB
    //   ints  : deg (N), adj (N*CAP)            = 26.0 MB
    float* G  = (float*)d_ws;
    float* H1 = G  + (size_t)N * 64;
    float* H2 = H1 + (size_t)N * 64;
    int* deg = (int*)(H2 + (size_t)N * 64);
    int* adj = deg + N;
    float* T3 = G;   // reuse G for layer-3 t = h2 @ W3 (N x 10)

    const int BLK = 256;

    // ---- Build ELL adjacency (once, reused by all 3 aggregations) ----
    hipMemsetAsync(deg, 0, (size_t)N * sizeof(int), stream);
    fill_adj_kernel<<<(E + BLK - 1) / BLK, BLK, 0, stream>>>(src, dst, deg, adj, E);

    // ---- Layer 1: d=32 -> 64, ReLU ----
    gather_kernel<32><<<(N * 8 + BLK - 1) / BLK, BLK, 0, stream>>>(x, deg, adj, G, N);
    node_mlp_kernel<32, 64, 4, true, true, true>
        <<<(N * 4 + BLK - 1) / BLK, BLK, 0, stream>>>(x, G, W1, b1, H1, N);

    // ---- Layer 2: d=64 -> 64, ReLU ----
    gather_kernel<64><<<(N * 16 + BLK - 1) / BLK, BLK, 0, stream>>>(H1, deg, adj, G, N);
    node_mlp_kernel<64, 64, 4, true, true, true>
        <<<(N * 4 + BLK - 1) / BLK, BLK, 0, stream>>>(H1, G, W2, b2, H2, N);

    // ---- Layer 3: t = h2 @ W3 (no bias/agg), then out = t + A t + b3 ----
    node_mlp_kernel<64, 10, 2, false, false, false>
        <<<(N * 2 + BLK - 1) / BLK, BLK, 0, stream>>>(H2, H2, W3, b3, T3, N);
    gather_final_kernel<<<(N * 16 + BLK - 1) / BLK, BLK, 0, stream>>>(
        T3, deg, adj, b3, out, N);
}

// Round 3
// 356.682 us; speedup vs baseline: 9.8395x; 1.0930x over previous
//
#include <hip/hip_runtime.h>

// GIN 3-layer: ELL adjacency + gather-side reduction, bf16 feature tables
// for the random gathers (fp32 accumulate), nontemporal adj fill.
// N=100000, E=1.6M, dims 32 -> 64 -> 64 -> 10, fp32 in/out.
// Layer 3 uses linearity: (h + A h) @ W3 + b3 == t + A t + b3, t = h @ W3,
// aggregated in padded 16-float rows (one cache line per neighbor read).

#define GIN_N 100000
#define CAP 64   // max in-degree capacity (mean 16; Poisson tail safe)

typedef unsigned short bfu;

__device__ __forceinline__ float bf_lo(unsigned int u) {
    return __uint_as_float(u << 16);
}
__device__ __forceinline__ float bf_hi(unsigned int u) {
    return __uint_as_float(u & 0xffff0000u);
}
__device__ __forceinline__ unsigned int f2bf(float f) {  // RNE
    unsigned int u = __float_as_uint(f);
    return (u + 0x7fffu + ((u >> 16) & 1u)) >> 16;
}

// ---- x (fp32) -> Xb (bf16), 8 elems/thread ----
__global__ void f2bf_kernel(const float* __restrict__ in,
                            bfu* __restrict__ out, int n8) {
    int t = blockIdx.x * blockDim.x + threadIdx.x;
    if (t >= n8) return;
    const float4* v = reinterpret_cast<const float4*>(in);
    float4 a = v[2 * t], b = v[2 * t + 1];
    uint4 p;
    p.x = f2bf(a.x) | (f2bf(a.y) << 16);
    p.y = f2bf(a.z) | (f2bf(a.w) << 16);
    p.z = f2bf(b.x) | (f2bf(b.y) << 16);
    p.w = f2bf(b.z) | (f2bf(b.w) << 16);
    reinterpret_cast<uint4*>(out)[t] = p;
}

// ---- ELL adjacency fill: nt loads for streamed edges, nt store for the
// scattered adj write (avoid L2 write-allocate thrash -> 96MB writeback). ----
__global__ void fill_adj_kernel(const int* __restrict__ src,
                                const int* __restrict__ dst,
                                int* __restrict__ deg,
                                int* __restrict__ adj, int E) {
    int e = blockIdx.x * blockDim.x + threadIdx.x;
    if (e >= E) return;
    int d = __builtin_nontemporal_load(&dst[e]);
    int s = __builtin_nontemporal_load(&src[e]);
    int pos = atomicAdd(&deg[d], 1);
    if (pos < CAP) __builtin_nontemporal_store(s, &adj[(size_t)d * CAP + pos]);
}

// ---- Gather-side aggregation over bf16 rows, fp32 accumulate.
// TPN = D/8 threads per node, 16B (8 bf16) per thread. ----
template <int D>
__global__ void gather_bf16_kernel(const bfu* __restrict__ feat,
                                   const int* __restrict__ deg,
                                   const int* __restrict__ adj,
                                   float* __restrict__ agg) {
    constexpr int TPN = D / 8;
    int t = blockIdx.x * blockDim.x + threadIdx.x;
    int n = t / TPN;
    int j = t - n * TPN;
    if (n >= GIN_N) return;
    int d = deg[n];
    const int* row = adj + (size_t)n * CAP;
    const uint4* f = reinterpret_cast<const uint4*>(feat);
    float acc[8] = {0, 0, 0, 0, 0, 0, 0, 0};
    int k = 0;
    for (; k + 1 < d; k += 2) {
        uint4 v0 = f[(size_t)row[k] * TPN + j];
        uint4 v1 = f[(size_t)row[k + 1] * TPN + j];
        acc[0] += bf_lo(v0.x) + bf_lo(v1.x);
        acc[1] += bf_hi(v0.x) + bf_hi(v1.x);
        acc[2] += bf_lo(v0.y) + bf_lo(v1.y);
        acc[3] += bf_hi(v0.y) + bf_hi(v1.y);
        acc[4] += bf_lo(v0.z) + bf_lo(v1.z);
        acc[5] += bf_hi(v0.z) + bf_hi(v1.z);
        acc[6] += bf_lo(v0.w) + bf_lo(v1.w);
        acc[7] += bf_hi(v0.w) + bf_hi(v1.w);
    }
    if (k < d) {
        uint4 v = f[(size_t)row[k] * TPN + j];
        acc[0] += bf_lo(v.x); acc[1] += bf_hi(v.x);
        acc[2] += bf_lo(v.y); acc[3] += bf_hi(v.y);
        acc[4] += bf_lo(v.z); acc[5] += bf_hi(v.z);
        acc[6] += bf_lo(v.w); acc[7] += bf_hi(v.w);
    }
    float4* o = reinterpret_cast<float4*>(agg + (size_t)n * D + j * 8);
    o[0] = make_float4(acc[0], acc[1], acc[2], acc[3]);
    o[1] = make_float4(acc[4], acc[5], acc[6], acc[7]);
}

// ---- Final aggregation in padded 16-float rows: out = t + A t + b3. ----
__global__ void gather_final_kernel(const float* __restrict__ t16,
                                    const int* __restrict__ deg,
                                    const int* __restrict__ adj,
                                    const float* __restrict__ b3,
                                    float* __restrict__ out) {
    int t = blockIdx.x * blockDim.x + threadIdx.x;
    int n = t >> 4;
    int j = t & 15;
    if (n >= GIN_N || j >= 10) return;
    int d = deg[n];
    const int* row = adj + (size_t)n * CAP;
    float acc = t16[(size_t)n * 16 + j];
    int k = 0;
    for (; k + 1 < d; k += 2)
        acc += t16[(size_t)row[k] * 16 + j] + t16[(size_t)row[k + 1] * 16 + j];
    if (k < d) acc += t16[(size_t)row[k] * 16 + j];
    out[(size_t)n * 10 + j] = acc + b3[j];
}

// ---- Per-node MLP: out[n] = act((x[n] [+ agg[n]]) @ W [+ b]).
// x either fp32 (xf) or bf16 (xb); agg fp32; out bf16 or fp32, row stride
// OSTRIDE. W,b staged in LDS; TPN threads/node, MT=M/TPN cols each. ----
template <int K, int M, int TPN, bool RELU, bool BIAS, bool AGG,
          bool XBF16, bool OBF16, int OSTRIDE>
__global__ void node_mlp_kernel(const float* __restrict__ xf,
                                const bfu* __restrict__ xb,
                                const float* __restrict__ agg,
                                const float* __restrict__ W,
                                const float* __restrict__ b,
                                void* __restrict__ out_) {
    constexpr int MT = M / TPN;
    __shared__ float Ws[K * M];
    __shared__ float bs[M];
    for (int i = threadIdx.x; i < K * M; i += blockDim.x) Ws[i] = W[i];
    if (BIAS)
        for (int i = threadIdx.x; i < M; i += blockDim.x) bs[i] = b[i];
    __syncthreads();

    int t = blockIdx.x * blockDim.x + threadIdx.x;
    int n = t / TPN;
    int sub = t - n * TPN;
    if (n >= GIN_N) return;

    float acc[MT];
#pragma unroll
    for (int jj = 0; jj < MT; ++jj) acc[jj] = BIAS ? bs[sub * MT + jj] : 0.0f;

#pragma unroll
    for (int kc = 0; kc < K / 8; ++kc) {
        float v[8];
        if (XBF16) {
            uint4 u = reinterpret_cast<const uint4*>(xb)[(size_t)n * (K / 8) + kc];
            v[0] = bf_lo(u.x); v[1] = bf_hi(u.x);
            v[2] = bf_lo(u.y); v[3] = bf_hi(u.y);
            v[4] = bf_lo(u.z); v[5] = bf_hi(u.z);
            v[6] = bf_lo(u.w); v[7] = bf_hi(u.w);
        } else {
            const float4* xv = reinterpret_cast<const float4*>(xf);
            float4 a = xv[(size_t)n * (K / 4) + 2 * kc];
            float4 c = xv[(size_t)n * (K / 4) + 2 * kc + 1];
            v[0] = a.x; v[1] = a.y; v[2] = a.z; v[3] = a.w;
            v[4] = c.x; v[5] = c.y; v[6] = c.z; v[7] = c.w;
        }
        if (AGG) {
            const float4* av = reinterpret_cast<const float4*>(agg);
            float4 a = av[(size_t)n * (K / 4) + 2 * kc];
            float4 c = av[(size_t)n * (K / 4) + 2 * kc + 1];
            v[0] += a.x; v[1] += a.y; v[2] += a.z; v[3] += a.w;
            v[4] += c.x; v[5] += c.y; v[6] += c.z; v[7] += c.w;
        }
#pragma unroll
        for (int kk = 0; kk < 8; ++kk) {
            const float* wr = &Ws[(kc * 8 + kk) * M + sub * MT];
#pragma unroll
            for (int jj = 0; jj < MT; ++jj)
                acc[jj] = fmaf(v[kk], wr[jj], acc[jj]);
        }
    }

#pragma unroll
    for (int jj = 0; jj < MT; ++jj)
        if (RELU) acc[jj] = fmaxf(acc[jj], 0.0f);

    if (OBF16) {
        bfu* o = (bfu*)out_ + (size_t)n * OSTRIDE + sub * MT;
#pragma unroll
        for (int jj = 0; jj < MT; jj += 2) {
            unsigned int p = f2bf(acc[jj]) | (f2bf(acc[jj + 1]) << 16);
            *reinterpret_cast<unsigned int*>(o + jj) = p;
        }
    } else {
        float* o = (float*)out_ + (size_t)n * OSTRIDE + sub * MT;
#pragma unroll
        for (int jj = 0; jj < MT; ++jj) o[jj] = acc[jj];
    }
}

extern "C" void kernel_launch(void* const* d_in, const int* in_sizes, int n_in,
                              void* d_out, int out_size, void* d_ws, size_t ws_size,
                              hipStream_t stream) {
    const float* x  = (const float*)d_in[0];
    const int*   ei = (const int*)d_in[1];
    const float* W1 = (const float*)d_in[2];
    const float* b1 = (const float*)d_in[3];
    const float* W2 = (const float*)d_in[4];
    const float* b2 = (const float*)d_in[5];
    const float* W3 = (const float*)d_in[6];
    const float* b3 = (const float*)d_in[7];
    float* out = (float*)d_out;

    const int N = GIN_N;
    const int E = in_sizes[1] / 2;   // edge_index is [2, E]
    const int* src = ei;
    const int* dst = ei + E;

    // Workspace layout (byte offsets, all 16B-aligned):
    //   G   fp32 N*64   = 25.6 MB   (agg buffer; T aliases it for layer 3)
    //   H1  bf16 N*64   = 12.8 MB
    //   H2  bf16 N*64   = 12.8 MB
    //   Xb  bf16 N*32   =  6.4 MB
    //   deg int  N      =  0.4 MB
    //   adj int  N*CAP  = 25.6 MB          total ~83.6 MB
    float* G  = (float*)d_ws;
    bfu* H1 = (bfu*)(G + (size_t)N * 64);
    bfu* H2 = H1 + (size_t)N * 64;
    bfu* Xb = H2 + (size_t)N * 64;
    int* deg = (int*)(Xb + (size_t)N * 32);
    int* adj = deg + N;
    float* T = G;  // N x 16 fp32, reuses G (free by layer 3)

    const int BLK = 256;

    // ---- Build ELL adjacency + bf16 copy of x ----
    hipMemsetAsync(deg, 0, (size_t)N * sizeof(int), stream);
    fill_adj_kernel<<<(E + BLK - 1) / BLK, BLK, 0, stream>>>(src, dst, deg, adj, E);
    f2bf_kernel<<<(N * 32 / 8 + BLK - 1) / BLK, BLK, 0, stream>>>(x, Xb, N * 32 / 8);

    // ---- Layer 1: d=32 -> 64, ReLU (gather bf16 x, self-term fp32 x) ----
    gather_bf16_kernel<32><<<(N * 4 + BLK - 1) / BLK, BLK, 0, stream>>>(Xb, deg, adj, G);
    node_mlp_kernel<32, 64, 4, true, true, true, false, true, 64>
        <<<(N * 4 + BLK - 1) / BLK, BLK, 0, stream>>>(x, nullptr, G, W1, b1, H1);

    // ---- Layer 2: d=64 -> 64, ReLU ----
    gather_bf16_kernel<64><<<(N * 8 + BLK - 1) / BLK, BLK, 0, stream>>>(H1, deg, adj, G);
    node_mlp_kernel<64, 64, 4, true, true, true, true, true, 64>
        <<<(N * 4 + BLK - 1) / BLK, BLK, 0, stream>>>(nullptr, H1, G, W2, b2, H2);

    // ---- Layer 3: t = h2 @ W3 (padded rows of 16), out = t + A t + b3 ----
    node_mlp_kernel<64, 10, 2, false, false, false, true, false, 16>
        <<<(N * 2 + BLK - 1) / BLK, BLK, 0, stream>>>(nullptr, H2, nullptr, W3, b3, T);
    gather_final_kernel<<<(N * 16 + BLK - 1) / BLK, BLK, 0, stream>>>(
        T, deg, adj, b3, out);
}

// Round 4
// 290.022 us; speedup vs baseline: 12.1011x; 1.2298x over previous
//
#include <hip/hip_runtime.h>

// GIN 3-layer: L2-blocked adjacency build (bucket-by-dst + XCD-affine fill),
// gather-side reduction over bf16 feature tables (fp32 accumulate).
// N=100000, E=1.6M, dims 32 -> 64 -> 64 -> 10, fp32 in/out.
// Layer 3 uses linearity: (h + A h) @ W3 + b3 == t + A t + b3, t = h @ W3,
// aggregated over bf16 t rows padded to 16 (32B, L2-resident 3.2 MB table).

#define GIN_N 100000
#define CAP 64        // ELL row capacity (mean deg 16; CAP=64 passed rounds 1-3)
#define NBUCKET 8     // dst-range buckets == XCD count
#define NB 12500      // nodes per bucket (N / NBUCKET)
#define EPT 16        // edges per thread in bucket pass

typedef unsigned short bfu;

__device__ __forceinline__ float bf_lo(unsigned int u) {
    return __uint_as_float(u << 16);
}
__device__ __forceinline__ float bf_hi(unsigned int u) {
    return __uint_as_float(u & 0xffff0000u);
}
__device__ __forceinline__ unsigned int f2bf(float f) {  // RNE
    unsigned int u = __float_as_uint(f);
    return (u + 0x7fffu + ((u >> 16) & 1u)) >> 16;
}

// ---- x (fp32) -> Xb (bf16), 8 elems/thread ----
__global__ void f2bf_kernel(const float* __restrict__ in,
                            bfu* __restrict__ out, int n8) {
    int t = blockIdx.x * blockDim.x + threadIdx.x;
    if (t >= n8) return;
    const float4* v = reinterpret_cast<const float4*>(in);
    float4 a = v[2 * t], b = v[2 * t + 1];
    uint4 p;
    p.x = f2bf(a.x) | (f2bf(a.y) << 16);
    p.y = f2bf(a.z) | (f2bf(a.w) << 16);
    p.z = f2bf(b.x) | (f2bf(b.y) << 16);
    p.w = f2bf(b.z) | (f2bf(b.w) << 16);
    reinterpret_cast<uint4*>(out)[t] = p;
}

// ---- Phase A: partition edges into NBUCKET dst-range buckets.
// Packed record: (dst - bucket*NB) << 17 | src   (14 + 17 = 31 bits).
// Per-block LDS histogram -> one cursor atomicAdd per bucket -> contiguous
// per-block runs (line-merged writes). ----
__global__ void bucket_kernel(const int* __restrict__ src,
                              const int* __restrict__ dst,
                              int E,
                              unsigned* __restrict__ bucketbuf, int bstride,
                              int* __restrict__ cursor) {
    __shared__ int h[NBUCKET];
    __shared__ int base[NBUCKET];
    int chunk0 = blockIdx.x * (blockDim.x * EPT);
    if (threadIdx.x < NBUCKET) h[threadIdx.x] = 0;
    __syncthreads();
    int myb[EPT];
#pragma unroll
    for (int i = 0; i < EPT; ++i) {
        int e = chunk0 + threadIdx.x + i * blockDim.x;
        if (e < E) {
            int b = dst[e] / NB;
            myb[i] = b;
            atomicAdd(&h[b], 1);
        } else {
            myb[i] = -1;
        }
    }
    __syncthreads();
    if (threadIdx.x < NBUCKET)
        base[threadIdx.x] = atomicAdd(&cursor[threadIdx.x], h[threadIdx.x]);
    __syncthreads();
    if (threadIdx.x < NBUCKET) h[threadIdx.x] = 0;
    __syncthreads();
#pragma unroll
    for (int i = 0; i < EPT; ++i) {
        int b = myb[i];
        if (b < 0) continue;
        int e = chunk0 + threadIdx.x + i * blockDim.x;
        int d = dst[e];
        int s = src[e];
        int pos = atomicAdd(&h[b], 1);
        unsigned rec = ((unsigned)(d - b * NB) << 17) | (unsigned)s;
        bucketbuf[(size_t)b * bstride + base[b] + pos] = rec;
    }
}

// ---- Phase B: fill ELL adjacency, one bucket per blockIdx&7 (XCD-affine
// heuristic). Each bucket's adj slice is 3.2 MB -> fits one XCD's 4 MB L2,
// so the ~16 slot-writes per line merge before eviction. ----
__global__ void fill_bucketed_kernel(const unsigned* __restrict__ bucketbuf,
                                     int bstride,
                                     const int* __restrict__ cursor,
                                     int* __restrict__ deg,
                                     int* __restrict__ adj) {
    int b = blockIdx.x & (NBUCKET - 1);
    int cnt = cursor[b];
    const unsigned* buf = bucketbuf + (size_t)b * bstride;
    int nblk = gridDim.x >> 3;
    int bi = blockIdx.x >> 3;
    for (int i = bi * blockDim.x + threadIdx.x; i < cnt;
         i += nblk * blockDim.x) {
        unsigned v = buf[i];
        int s = (int)(v & 0x1FFFFu);
        int node = b * NB + (int)(v >> 17);
        int pos = atomicAdd(&deg[node], 1);
        if (pos < CAP) adj[(size_t)node * CAP + pos] = s;
    }
}

// ---- Gather-side aggregation over bf16 rows, fp32 accumulate.
// TPN = D/8 threads per node, 16B (8 bf16) per thread; int4 adj-row loads,
// 4x unrolled neighbor loop for ILP. ----
template <int D>
__global__ void gather_bf16_kernel(const bfu* __restrict__ feat,
                                   const int* __restrict__ deg,
                                   const int* __restrict__ adj,
                                   float* __restrict__ agg) {
    constexpr int TPN = D / 8;
    int t = blockIdx.x * blockDim.x + threadIdx.x;
    int n = t / TPN;
    int j = t - n * TPN;
    if (n >= GIN_N) return;
    int d = deg[n];
    const int* row = adj + (size_t)n * CAP;
    const uint4* f = reinterpret_cast<const uint4*>(feat);
    float acc[8] = {0, 0, 0, 0, 0, 0, 0, 0};
    int k = 0;
    for (; k + 4 <= d; k += 4) {
        int4 r = *reinterpret_cast<const int4*>(row + k);  // 16B-aligned
        uint4 v0 = f[(size_t)r.x * TPN + j];
        uint4 v1 = f[(size_t)r.y * TPN + j];
        uint4 v2 = f[(size_t)r.z * TPN + j];
        uint4 v3 = f[(size_t)r.w * TPN + j];
        acc[0] += bf_lo(v0.x) + bf_lo(v1.x) + bf_lo(v2.x) + bf_lo(v3.x);
        acc[1] += bf_hi(v0.x) + bf_hi(v1.x) + bf_hi(v2.x) + bf_hi(v3.x);
        acc[2] += bf_lo(v0.y) + bf_lo(v1.y) + bf_lo(v2.y) + bf_lo(v3.y);
        acc[3] += bf_hi(v0.y) + bf_hi(v1.y) + bf_hi(v2.y) + bf_hi(v3.y);
        acc[4] += bf_lo(v0.z) + bf_lo(v1.z) + bf_lo(v2.z) + bf_lo(v3.z);
        acc[5] += bf_hi(v0.z) + bf_hi(v1.z) + bf_hi(v2.z) + bf_hi(v3.z);
        acc[6] += bf_lo(v0.w) + bf_lo(v1.w) + bf_lo(v2.w) + bf_lo(v3.w);
        acc[7] += bf_hi(v0.w) + bf_hi(v1.w) + bf_hi(v2.w) + bf_hi(v3.w);
    }
    for (; k < d; ++k) {
        uint4 v = f[(size_t)row[k] * TPN + j];
        acc[0] += bf_lo(v.x); acc[1] += bf_hi(v.x);
        acc[2] += bf_lo(v.y); acc[3] += bf_hi(v.y);
        acc[4] += bf_lo(v.z); acc[5] += bf_hi(v.z);
        acc[6] += bf_lo(v.w); acc[7] += bf_hi(v.w);
    }
    float4* o = reinterpret_cast<float4*>(agg + (size_t)n * D + j * 8);
    o[0] = make_float4(acc[0], acc[1], acc[2], acc[3]);
    o[1] = make_float4(acc[4], acc[5], acc[6], acc[7]);
}

// ---- Final aggregation over bf16 t rows (padded to 16 halves = 8 uints):
// out = t + A t + b3. TPN=8, active j<5, each thread owns 2 dims. ----
__global__ void gather_final_kernel(const unsigned* __restrict__ t8,
                                    const int* __restrict__ deg,
                                    const int* __restrict__ adj,
                                    const float* __restrict__ b3,
                                    float* __restrict__ out) {
    int t = blockIdx.x * blockDim.x + threadIdx.x;
    int n = t >> 3;
    int j = t & 7;
    if (n >= GIN_N || j >= 5) return;
    int d = deg[n];
    const int* row = adj + (size_t)n * CAP;
    unsigned sv = t8[(size_t)n * 8 + j];
    float a0 = bf_lo(sv), a1 = bf_hi(sv);
    int k = 0;
    for (; k + 4 <= d; k += 4) {
        int4 r = *reinterpret_cast<const int4*>(row + k);
        unsigned v0 = t8[(size_t)r.x * 8 + j];
        unsigned v1 = t8[(size_t)r.y * 8 + j];
        unsigned v2 = t8[(size_t)r.z * 8 + j];
        unsigned v3 = t8[(size_t)r.w * 8 + j];
        a0 += bf_lo(v0) + bf_lo(v1) + bf_lo(v2) + bf_lo(v3);
        a1 += bf_hi(v0) + bf_hi(v1) + bf_hi(v2) + bf_hi(v3);
    }
    for (; k < d; ++k) {
        unsigned v = t8[(size_t)row[k] * 8 + j];
        a0 += bf_lo(v); a1 += bf_hi(v);
    }
    out[(size_t)n * 10 + 2 * j] = a0 + b3[2 * j];
    out[(size_t)n * 10 + 2 * j + 1] = a1 + b3[2 * j + 1];
}

// ---- Per-node MLP: out[n] = act((x[n] [+ agg[n]]) @ W [+ b]). ----
template <int K, int M, int TPN, bool RELU, bool BIAS, bool AGG,
          bool XBF16, bool OBF16, int OSTRIDE>
__global__ void node_mlp_kernel(const float* __restrict__ xf,
                                const bfu* __restrict__ xb,
                                const float* __restrict__ agg,
                                const float* __restrict__ W,
                                const float* __restrict__ b,
                                void* __restrict__ out_) {
    constexpr int MT = M / TPN;
    __shared__ float Ws[K * M];
    __shared__ float bs[M];
    for (int i = threadIdx.x; i < K * M; i += blockDim.x) Ws[i] = W[i];
    if (BIAS)
        for (int i = threadIdx.x; i < M; i += blockDim.x) bs[i] = b[i];
    __syncthreads();

    int t = blockIdx.x * blockDim.x + threadIdx.x;
    int n = t / TPN;
    int sub = t - n * TPN;
    if (n >= GIN_N) return;

    float acc[MT];
#pragma unroll
    for (int jj = 0; jj < MT; ++jj) acc[jj] = BIAS ? bs[sub * MT + jj] : 0.0f;

#pragma unroll
    for (int kc = 0; kc < K / 8; ++kc) {
        float v[8];
        if (XBF16) {
            uint4 u = reinterpret_cast<const uint4*>(xb)[(size_t)n * (K / 8) + kc];
            v[0] = bf_lo(u.x); v[1] = bf_hi(u.x);
            v[2] = bf_lo(u.y); v[3] = bf_hi(u.y);
            v[4] = bf_lo(u.z); v[5] = bf_hi(u.z);
            v[6] = bf_lo(u.w); v[7] = bf_hi(u.w);
        } else {
            const float4* xv = reinterpret_cast<const float4*>(xf);
            float4 a = xv[(size_t)n * (K / 4) + 2 * kc];
            float4 c = xv[(size_t)n * (K / 4) + 2 * kc + 1];
            v[0] = a.x; v[1] = a.y; v[2] = a.z; v[3] = a.w;
            v[4] = c.x; v[5] = c.y; v[6] = c.z; v[7] = c.w;
        }
        if (AGG) {
            const float4* av = reinterpret_cast<const float4*>(agg);
            float4 a = av[(size_t)n * (K / 4) + 2 * kc];
            float4 c = av[(size_t)n * (K / 4) + 2 * kc + 1];
            v[0] += a.x; v[1] += a.y; v[2] += a.z; v[3] += a.w;
            v[4] += c.x; v[5] += c.y; v[6] += c.z; v[7] += c.w;
        }
#pragma unroll
        for (int kk = 0; kk < 8; ++kk) {
            const float* wr = &Ws[(kc * 8 + kk) * M + sub * MT];
#pragma unroll
            for (int jj = 0; jj < MT; ++jj)
                acc[jj] = fmaf(v[kk], wr[jj], acc[jj]);
        }
    }

#pragma unroll
    for (int jj = 0; jj < MT; ++jj)
        if (RELU) acc[jj] = fmaxf(acc[jj], 0.0f);

    if (OBF16) {
        bfu* o = (bfu*)out_ + (size_t)n * OSTRIDE + sub * MT;
        if constexpr (MT % 2 == 0) {
#pragma unroll
            for (int jj = 0; jj < MT; jj += 2) {
                unsigned int p = f2bf(acc[jj]) | (f2bf(acc[jj + 1]) << 16);
                *reinterpret_cast<unsigned int*>(o + jj) = p;
            }
        } else {
#pragma unroll
            for (int jj = 0; jj < MT; ++jj) o[jj] = (bfu)f2bf(acc[jj]);
        }
    } else {
        float* o = (float*)out_ + (size_t)n * OSTRIDE + sub * MT;
#pragma unroll
        for (int jj = 0; jj < MT; ++jj) o[jj] = acc[jj];
    }
}

extern "C" void kernel_launch(void* const* d_in, const int* in_sizes, int n_in,
                              void* d_out, int out_size, void* d_ws, size_t ws_size,
                              hipStream_t stream) {
    const float* x  = (const float*)d_in[0];
    const int*   ei = (const int*)d_in[1];
    const float* W1 = (const float*)d_in[2];
    const float* b1 = (const float*)d_in[3];
    const float* W2 = (const float*)d_in[4];
    const float* b2 = (const float*)d_in[5];
    const float* W3 = (const float*)d_in[6];
    const float* b3 = (const float*)d_in[7];
    float* out = (float*)d_out;

    const int N = GIN_N;
    const int E = in_sizes[1] / 2;   // edge_index is [2, E]
    const int* src = ei;
    const int* dst = ei + E;

    // Workspace layout (all segments 16B-aligned):
    //   G   fp32 N*64        25.6 MB   (agg buffer)
    //   H1  bf16 N*64        12.8 MB
    //   H2  bf16 N*64        12.8 MB
    //   Xb  bf16 N*32         6.4 MB
    //   Tb  bf16 N*16         3.2 MB   (layer-3 t, padded rows)
    //   deg int  N            0.4 MB
    //   cur int  8
    //   adj int  N*CAP       25.6 MB
    //   bkt uint 8*bstride   ~7.5 MB          total ~94.3 MB
    float* G  = (float*)d_ws;
    bfu* H1 = (bfu*)(G + (size_t)N * 64);
    bfu* H2 = H1 + (size_t)N * 64;
    bfu* Xb = H2 + (size_t)N * 64;
    bfu* Tb = Xb + (size_t)N * 32;
    int* deg = (int*)(Tb + (size_t)N * 16);
    int* cursor = deg + N;
    int* adj = cursor + 8;
    unsigned* bucketbuf = (unsigned*)(adj + (size_t)N * CAP);
    const int bstride = E / NBUCKET + 32768;

    const int BLK = 256;

    // ---- Adjacency build: zero deg+cursor, bucket, XCD-affine fill ----
    hipMemsetAsync(deg, 0, (size_t)(N + 8) * sizeof(int), stream);
    {
        int chunk = BLK * EPT;
        bucket_kernel<<<(E + chunk - 1) / chunk, BLK, 0, stream>>>(
            src, dst, E, bucketbuf, bstride, cursor);
        fill_bucketed_kernel<<<1024, BLK, 0, stream>>>(
            bucketbuf, bstride, cursor, deg, adj);
    }
    f2bf_kernel<<<(N * 32 / 8 + BLK - 1) / BLK, BLK, 0, stream>>>(x, Xb, N * 32 / 8);

    // ---- Layer 1: d=32 -> 64, ReLU (gather bf16 x, self-term fp32 x) ----
    gather_bf16_kernel<32><<<(N * 4 + BLK - 1) / BLK, BLK, 0, stream>>>(Xb, deg, adj, G);
    node_mlp_kernel<32, 64, 4, true, true, true, false, true, 64>
        <<<(N * 4 + BLK - 1) / BLK, BLK, 0, stream>>>(x, nullptr, G, W1, b1, H1);

    // ---- Layer 2: d=64 -> 64, ReLU ----
    gather_bf16_kernel<64><<<(N * 8 + BLK - 1) / BLK, BLK, 0, stream>>>(H1, deg, adj, G);
    node_mlp_kernel<64, 64, 4, true, true, true, true, true, 64>
        <<<(N * 4 + BLK - 1) / BLK, BLK, 0, stream>>>(nullptr, H1, G, W2, b2, H2);

    // ---- Layer 3: t = h2 @ W3 (bf16, padded 16), out = t + A t + b3 ----
    node_mlp_kernel<64, 10, 2, false, false, false, true, true, 16>
        <<<(N * 2 + BLK - 1) / BLK, BLK, 0, stream>>>(nullptr, H2, nullptr, W3, b3, Tb);
    gather_final_kernel<<<(N * 8 + BLK - 1) / BLK, BLK, 0, stream>>>(
        (const unsigned*)Tb, deg, adj, b3, out);
}

// Round 5
// 238.142 us; speedup vs baseline: 14.7373x; 1.2179x over previous
//
#include <hip/hip_runtime.h>

// GIN 3-layer: bucket + LDS-staged CSR adjacency build (sequential writes,
// no line-eviction amplification), gather-side reduction over bf16 feature
// tables (fp32 accumulate).
// N=100000, E=1.6M, dims 32 -> 64 -> 64 -> 10, fp32 in/out.
// Layer 3: (h + A h) @ W3 + b3 == t + A t + b3 with t = h @ W3, aggregated
// over bf16 t rows padded to 16 halves (32B; 3.2 MB L2/L3-resident table).

#define GIN_N 100000
#define NBUCKET 256
#define NB2 391        // ceil(N / NBUCKET); local id < 391 fits 9 bits
#define BSTRIDE 8192   // bucket capacity (mean 6250, sigma ~79)
#define EPT 16         // edges per thread in bucket pass

typedef unsigned short bfu;

__device__ __forceinline__ float bf_lo(unsigned int u) {
    return __uint_as_float(u << 16);
}
__device__ __forceinline__ float bf_hi(unsigned int u) {
    return __uint_as_float(u & 0xffff0000u);
}
__device__ __forceinline__ unsigned int f2bf(float f) {  // RNE
    unsigned int u = __float_as_uint(f);
    return (u + 0x7fffu + ((u >> 16) & 1u)) >> 16;
}

// Exclusive Blelloch scan over S (pow2) ints in LDS, 256 threads.
template <int S>
__device__ __forceinline__ void blelloch_excl(int* a) {
#pragma unroll
    for (int d = 1; d < S; d <<= 1) {
        __syncthreads();
        int idx = (threadIdx.x + 1) * (d << 1) - 1;
        if (idx < S) a[idx] += a[idx - d];
    }
    __syncthreads();
    if (threadIdx.x == 0) a[S - 1] = 0;
#pragma unroll
    for (int d = S >> 1; d >= 1; d >>= 1) {
        __syncthreads();
        int idx = (threadIdx.x + 1) * (d << 1) - 1;
        if (idx < S) {
            int t = a[idx - d];
            a[idx - d] = a[idx];
            a[idx] += t;
        }
    }
    __syncthreads();
}

// ---- x (fp32) -> Xb (bf16), 8 elems/thread ----
__global__ void f2bf_kernel(const float* __restrict__ in,
                            bfu* __restrict__ out, int n8) {
    int t = blockIdx.x * blockDim.x + threadIdx.x;
    if (t >= n8) return;
    const float4* v = reinterpret_cast<const float4*>(in);
    float4 a = v[2 * t], b = v[2 * t + 1];
    uint4 p;
    p.x = f2bf(a.x) | (f2bf(a.y) << 16);
    p.y = f2bf(a.z) | (f2bf(a.w) << 16);
    p.z = f2bf(b.x) | (f2bf(b.y) << 16);
    p.w = f2bf(b.z) | (f2bf(b.w) << 16);
    reinterpret_cast<uint4*>(out)[t] = p;
}

// ---- Phase A: partition edges into 256 dst-range buckets.
// Record: (dst - b*NB2) << 17 | src  (9 + 17 bits). Per-block LDS histogram
// -> one cursor atomicAdd per bucket -> short contiguous runs. ----
__global__ __launch_bounds__(256) void bucket_kernel(
        const int* __restrict__ src, const int* __restrict__ dst, int E,
        unsigned* __restrict__ bucketbuf, int* __restrict__ cursor) {
    __shared__ int h[NBUCKET];
    __shared__ int base[NBUCKET];
    int tid = threadIdx.x;
    int chunk0 = blockIdx.x * (256 * EPT);
    h[tid] = 0;
    __syncthreads();
    int myb[EPT];
    unsigned myrec[EPT];
#pragma unroll
    for (int i = 0; i < EPT; ++i) {
        int e = chunk0 + tid + i * 256;
        if (e < E) {
            int d = dst[e];
            int s = src[e];
            int b = d / NB2;            // constexpr divisor -> magic mul
            myb[i] = b;
            myrec[i] = ((unsigned)(d - b * NB2) << 17) | (unsigned)s;
            atomicAdd(&h[b], 1);
        } else {
            myb[i] = -1;
        }
    }
    __syncthreads();
    base[tid] = atomicAdd(&cursor[tid], h[tid]);
    h[tid] = 0;
    __syncthreads();
#pragma unroll
    for (int i = 0; i < EPT; ++i) {
        int b = myb[i];
        if (b < 0) continue;
        int pos = base[b] + atomicAdd(&h[b], 1);
        if (pos < BSTRIDE) bucketbuf[(size_t)b * BSTRIDE + pos] = myrec[i];
    }
}

// ---- Phase B: one block per bucket. Count degs in LDS, scan, scatter into
// LDS CSR slice, then stream out sequentially (zero write amplification).
// Bucket base = in-block exclusive scan of all 256 cursors. ----
__global__ __launch_bounds__(256) void csr_build_kernel(
        const unsigned* __restrict__ bucketbuf,
        const int* __restrict__ cursor,
        int* __restrict__ rowptr,
        int* __restrict__ adj) {
    __shared__ int csr[BSTRIDE];   // 32 KB
    __shared__ int cnt[512];
    __shared__ int off[512];
    __shared__ int bscan[NBUCKET];
    int b = blockIdx.x;
    int tid = threadIdx.x;
    bscan[tid] = cursor[tid];
    int mycnt = cursor[b];
    if (mycnt > BSTRIDE) mycnt = BSTRIDE;
    blelloch_excl<NBUCKET>(bscan);
    int base = bscan[b];

    const unsigned* buf = bucketbuf + (size_t)b * BSTRIDE;
    cnt[tid] = 0;
    cnt[tid + 256] = 0;
    __syncthreads();
    for (int i = tid; i < mycnt; i += 256)
        atomicAdd(&cnt[buf[i] >> 17], 1);
    __syncthreads();
    off[tid] = cnt[tid];
    off[tid + 256] = cnt[tid + 256];
    blelloch_excl<512>(off);

    // rowptr (including rowptr[N] via last bucket's pad slot)
    int nodes0 = b * NB2;
    int nn2 = GIN_N + 1 - nodes0;
    if (nn2 > NB2) nn2 = NB2;
    for (int l = tid; l < nn2; l += 256) rowptr[nodes0 + l] = base + off[l];
    __syncthreads();  // off reads done before scatter mutates it

    for (int i = tid; i < mycnt; i += 256) {
        unsigned r = buf[i];
        int pos = atomicAdd(&off[r >> 17], 1);
        csr[pos] = (int)(r & 0x1FFFFu);
    }
    __syncthreads();
    for (int i = tid; i < mycnt; i += 256) adj[base + i] = csr[i];
}

// ---- Gather-side aggregation over bf16 rows (CSR), fp32 accumulate.
// TPN = D/8 threads per node, 16B (8 bf16) per thread, 4x neighbor unroll. ----
template <int D>
__global__ void gather_bf16_kernel(const bfu* __restrict__ feat,
                                   const int* __restrict__ rowptr,
                                   const int* __restrict__ adj,
                                   float* __restrict__ agg) {
    constexpr int TPN = D / 8;
    int t = blockIdx.x * blockDim.x + threadIdx.x;
    int n = t / TPN;
    int j = t - n * TPN;
    if (n >= GIN_N) return;
    int start = rowptr[n];
    int d = rowptr[n + 1] - start;
    const int* row = adj + start;
    const uint4* f = reinterpret_cast<const uint4*>(feat);
    float acc[8] = {0, 0, 0, 0, 0, 0, 0, 0};
    int k = 0;
    for (; k + 4 <= d; k += 4) {
        int r0 = row[k], r1 = row[k + 1], r2 = row[k + 2], r3 = row[k + 3];
        uint4 v0 = f[(size_t)r0 * TPN + j];
        uint4 v1 = f[(size_t)r1 * TPN + j];
        uint4 v2 = f[(size_t)r2 * TPN + j];
        uint4 v3 = f[(size_t)r3 * TPN + j];
        acc[0] += bf_lo(v0.x) + bf_lo(v1.x) + bf_lo(v2.x) + bf_lo(v3.x);
        acc[1] += bf_hi(v0.x) + bf_hi(v1.x) + bf_hi(v2.x) + bf_hi(v3.x);
        acc[2] += bf_lo(v0.y) + bf_lo(v1.y) + bf_lo(v2.y) + bf_lo(v3.y);
        acc[3] += bf_hi(v0.y) + bf_hi(v1.y) + bf_hi(v2.y) + bf_hi(v3.y);
        acc[4] += bf_lo(v0.z) + bf_lo(v1.z) + bf_lo(v2.z) + bf_lo(v3.z);
        acc[5] += bf_hi(v0.z) + bf_hi(v1.z) + bf_hi(v2.z) + bf_hi(v3.z);
        acc[6] += bf_lo(v0.w) + bf_lo(v1.w) + bf_lo(v2.w) + bf_lo(v3.w);
        acc[7] += bf_hi(v0.w) + bf_hi(v1.w) + bf_hi(v2.w) + bf_hi(v3.w);
    }
    for (; k < d; ++k) {
        uint4 v = f[(size_t)row[k] * TPN + j];
        acc[0] += bf_lo(v.x); acc[1] += bf_hi(v.x);
        acc[2] += bf_lo(v.y); acc[3] += bf_hi(v.y);
        acc[4] += bf_lo(v.z); acc[5] += bf_hi(v.z);
        acc[6] += bf_lo(v.w); acc[7] += bf_hi(v.w);
    }
    float4* o = reinterpret_cast<float4*>(agg + (size_t)n * D + j * 8);
    o[0] = make_float4(acc[0], acc[1], acc[2], acc[3]);
    o[1] = make_float4(acc[4], acc[5], acc[6], acc[7]);
}

// ---- Final aggregation over bf16 t rows (padded to 16 halves = 8 uints):
// out = t + A t + b3. 8 threads/node, active j<5, 2 dims each. ----
__global__ void gather_final_kernel(const unsigned* __restrict__ t8,
                                    const int* __restrict__ rowptr,
                                    const int* __restrict__ adj,
                                    const float* __restrict__ b3,
                                    float* __restrict__ out) {
    int t = blockIdx.x * blockDim.x + threadIdx.x;
    int n = t >> 3;
    int j = t & 7;
    if (n >= GIN_N || j >= 5) return;
    int start = rowptr[n];
    int d = rowptr[n + 1] - start;
    const int* row = adj + start;
    unsigned sv = t8[(size_t)n * 8 + j];
    float a0 = bf_lo(sv), a1 = bf_hi(sv);
    int k = 0;
    for (; k + 4 <= d; k += 4) {
        int r0 = row[k], r1 = row[k + 1], r2 = row[k + 2], r3 = row[k + 3];
        unsigned v0 = t8[(size_t)r0 * 8 + j];
        unsigned v1 = t8[(size_t)r1 * 8 + j];
        unsigned v2 = t8[(size_t)r2 * 8 + j];
        unsigned v3 = t8[(size_t)r3 * 8 + j];
        a0 += bf_lo(v0) + bf_lo(v1) + bf_lo(v2) + bf_lo(v3);
        a1 += bf_hi(v0) + bf_hi(v1) + bf_hi(v2) + bf_hi(v3);
    }
    for (; k < d; ++k) {
        unsigned v = t8[(size_t)row[k] * 8 + j];
        a0 += bf_lo(v); a1 += bf_hi(v);
    }
    out[(size_t)n * 10 + 2 * j] = a0 + b3[2 * j];
    out[(size_t)n * 10 + 2 * j + 1] = a1 + b3[2 * j + 1];
}

// ---- Per-node MLP: out[n] = act((x[n] [+ agg[n]]) @ W [+ b]). ----
template <int K, int M, int TPN, bool RELU, bool BIAS, bool AGG,
          bool XBF16, bool OBF16, int OSTRIDE>
__global__ void node_mlp_kernel(const float* __restrict__ xf,
                                const bfu* __restrict__ xb,
                                const float* __restrict__ agg,
                                const float* __restrict__ W,
                                const float* __restrict__ b,
                                void* __restrict__ out_) {
    constexpr int MT = M / TPN;
    __shared__ float Ws[K * M];
    __shared__ float bs[M];
    for (int i = threadIdx.x; i < K * M; i += blockDim.x) Ws[i] = W[i];
    if (BIAS)
        for (int i = threadIdx.x; i < M; i += blockDim.x) bs[i] = b[i];
    __syncthreads();

    int t = blockIdx.x * blockDim.x + threadIdx.x;
    int n = t / TPN;
    int sub = t - n * TPN;
    if (n >= GIN_N) return;

    float acc[MT];
#pragma unroll
    for (int jj = 0; jj < MT; ++jj) acc[jj] = BIAS ? bs[sub * MT + jj] : 0.0f;

#pragma unroll
    for (int kc = 0; kc < K / 8; ++kc) {
        float v[8];
        if (XBF16) {
            uint4 u = reinterpret_cast<const uint4*>(xb)[(size_t)n * (K / 8) + kc];
            v[0] = bf_lo(u.x); v[1] = bf_hi(u.x);
            v[2] = bf_lo(u.y); v[3] = bf_hi(u.y);
            v[4] = bf_lo(u.z); v[5] = bf_hi(u.z);
            v[6] = bf_lo(u.w); v[7] = bf_hi(u.w);
        } else {
            const float4* xv = reinterpret_cast<const float4*>(xf);
            float4 a = xv[(size_t)n * (K / 4) + 2 * kc];
            float4 c = xv[(size_t)n * (K / 4) + 2 * kc + 1];
            v[0] = a.x; v[1] = a.y; v[2] = a.z; v[3] = a.w;
            v[4] = c.x; v[5] = c.y; v[6] = c.z; v[7] = c.w;
        }
        if (AGG) {
            const float4* av = reinterpret_cast<const float4*>(agg);
            float4 a = av[(size_t)n * (K / 4) + 2 * kc];
            float4 c = av[(size_t)n * (K / 4) + 2 * kc + 1];
            v[0] += a.x; v[1] += a.y; v[2] += a.z; v[3] += a.w;
            v[4] += c.x; v[5] += c.y; v[6] += c.z; v[7] += c.w;
        }
#pragma unroll
        for (int kk = 0; kk < 8; ++kk) {
            const float* wr = &Ws[(kc * 8 + kk) * M + sub * MT];
#pragma unroll
            for (int jj = 0; jj < MT; ++jj)
                acc[jj] = fmaf(v[kk], wr[jj], acc[jj]);
        }
    }

#pragma unroll
    for (int jj = 0; jj < MT; ++jj)
        if (RELU) acc[jj] = fmaxf(acc[jj], 0.0f);

    if (OBF16) {
        bfu* o = (bfu*)out_ + (size_t)n * OSTRIDE + sub * MT;
        if constexpr (MT % 2 == 0) {
#pragma unroll
            for (int jj = 0; jj < MT; jj += 2) {
                unsigned int p = f2bf(acc[jj]) | (f2bf(acc[jj + 1]) << 16);
                *reinterpret_cast<unsigned int*>(o + jj) = p;
            }
        } else {
#pragma unroll
            for (int jj = 0; jj < MT; ++jj) o[jj] = (bfu)f2bf(acc[jj]);
        }
    } else {
        float* o = (float*)out_ + (size_t)n * OSTRIDE + sub * MT;
#pragma unroll
        for (int jj = 0; jj < MT; ++jj) o[jj] = acc[jj];
    }
}

extern "C" void kernel_launch(void* const* d_in, const int* in_sizes, int n_in,
                              void* d_out, int out_size, void* d_ws, size_t ws_size,
                              hipStream_t stream) {
    const float* x  = (const float*)d_in[0];
    const int*   ei = (const int*)d_in[1];
    const float* W1 = (const float*)d_in[2];
    const float* b1 = (const float*)d_in[3];
    const float* W2 = (const float*)d_in[4];
    const float* b2 = (const float*)d_in[5];
    const float* W3 = (const float*)d_in[6];
    const float* b3 = (const float*)d_in[7];
    float* out = (float*)d_out;

    const int N = GIN_N;
    const int E = in_sizes[1] / 2;   // edge_index is [2, E]
    const int* src = ei;
    const int* dst = ei + E;

    // Workspace layout (segments 16B-aligned):
    //   G       fp32 N*64            25.6 MB  (agg buffer)
    //   H1      bf16 N*64            12.8 MB
    //   H2      bf16 N*64            12.8 MB
    //   Xb      bf16 N*32             6.4 MB
    //   Tb      bf16 N*16             3.2 MB  (layer-3 t, padded rows)
    //   rowptr  int  N+8              0.4 MB
    //   cursor  int  256
    //   adj     int  E                6.4 MB  (packed CSR)
    //   bkt     uint 256*BSTRIDE      8.4 MB          total ~76 MB
    float* G  = (float*)d_ws;
    bfu* H1 = (bfu*)(G + (size_t)N * 64);
    bfu* H2 = H1 + (size_t)N * 64;
    bfu* Xb = H2 + (size_t)N * 64;
    bfu* Tb = Xb + (size_t)N * 32;
    int* rowptr = (int*)(Tb + (size_t)N * 16);
    int* cursor = rowptr + (N + 8);
    int* adj = cursor + 256;
    unsigned* bucketbuf = (unsigned*)(adj + (size_t)E);

    const int BLK = 256;

    // ---- Adjacency build: bucket -> LDS-staged CSR ----
    hipMemsetAsync(cursor, 0, 256 * sizeof(int), stream);
    {
        int chunk = BLK * EPT;
        bucket_kernel<<<(E + chunk - 1) / chunk, BLK, 0, stream>>>(
            src, dst, E, bucketbuf, cursor);
        csr_build_kernel<<<NBUCKET, BLK, 0, stream>>>(
            bucketbuf, cursor, rowptr, adj);
    }
    f2bf_kernel<<<(N * 32 / 8 + BLK - 1) / BLK, BLK, 0, stream>>>(x, Xb, N * 32 / 8);

    // ---- Layer 1: d=32 -> 64, ReLU (gather bf16 x, self-term fp32 x) ----
    gather_bf16_kernel<32><<<(N * 4 + BLK - 1) / BLK, BLK, 0, stream>>>(
        Xb, rowptr, adj, G);
    node_mlp_kernel<32, 64, 4, true, true, true, false, true, 64>
        <<<(N * 4 + BLK - 1) / BLK, BLK, 0, stream>>>(x, nullptr, G, W1, b1, H1);

    // ---- Layer 2: d=64 -> 64, ReLU ----
    gather_bf16_kernel<64><<<(N * 8 + BLK - 1) / BLK, BLK, 0, stream>>>(
        H1, rowptr, adj, G);
    node_mlp_kernel<64, 64, 4, true, true, true, true, true, 64>
        <<<(N * 4 + BLK - 1) / BLK, BLK, 0, stream>>>(nullptr, H1, G, W2, b2, H2);

    // ---- Layer 3: t = h2 @ W3 (bf16, padded 16), out = t + A t + b3 ----
    node_mlp_kernel<64, 10, 2, false, false, false, true, true, 16>
        <<<(N * 2 + BLK - 1) / BLK, BLK, 0, stream>>>(nullptr, H2, nullptr, W3, b3, Tb);
    gather_final_kernel<<<(N * 8 + BLK - 1) / BLK, BLK, 0, stream>>>(
        (const unsigned*)Tb, rowptr, adj, b3, out);
}

// Round 6
// 222.136 us; speedup vs baseline: 15.7992x; 1.0721x over previous
//
#include <hip/hip_runtime.h>

// GIN 3-layer: bucket + LDS-staged CSR build, then per layer a FUSED
// gather+MLP kernel (agg rows staged in a padded LDS tile; no global agg
// buffer, no separate MLP dispatch).
// N=100000, E=1.6M, dims 32 -> 64 -> 64 -> 10, fp32 in/out.
// Layer 3: (h + A h) @ W3 + b3 == t + A t + b3 with t = h @ W3, aggregated
// over bf16 t rows padded to 16 halves (32B; 3.2 MB L2/L3-resident table).

#define GIN_N 100000
#define NBUCKET 256
#define NB2 391        // ceil(N / NBUCKET); local id < 391 fits 9 bits
#define BSTRIDE 8192   // bucket capacity (mean 6250, sigma ~79)
#define EPT 16         // edges per thread in bucket pass

typedef unsigned short bfu;

__device__ __forceinline__ float bf_lo(unsigned int u) {
    return __uint_as_float(u << 16);
}
__device__ __forceinline__ float bf_hi(unsigned int u) {
    return __uint_as_float(u & 0xffff0000u);
}
__device__ __forceinline__ unsigned int f2bf(float f) {  // RNE
    unsigned int u = __float_as_uint(f);
    return (u + 0x7fffu + ((u >> 16) & 1u)) >> 16;
}

// Exclusive Blelloch scan over S (pow2) ints in LDS, 256 threads.
template <int S>
__device__ __forceinline__ void blelloch_excl(int* a) {
#pragma unroll
    for (int d = 1; d < S; d <<= 1) {
        __syncthreads();
        int idx = (threadIdx.x + 1) * (d << 1) - 1;
        if (idx < S) a[idx] += a[idx - d];
    }
    __syncthreads();
    if (threadIdx.x == 0) a[S - 1] = 0;
#pragma unroll
    for (int d = S >> 1; d >= 1; d >>= 1) {
        __syncthreads();
        int idx = (threadIdx.x + 1) * (d << 1) - 1;
        if (idx < S) {
            int t = a[idx - d];
            a[idx - d] = a[idx];
            a[idx] += t;
        }
    }
    __syncthreads();
}

// ---- x (fp32) -> Xb (bf16), 8 elems/thread ----
__global__ void f2bf_kernel(const float* __restrict__ in,
                            bfu* __restrict__ out, int n8) {
    int t = blockIdx.x * blockDim.x + threadIdx.x;
    if (t >= n8) return;
    const float4* v = reinterpret_cast<const float4*>(in);
    float4 a = v[2 * t], b = v[2 * t + 1];
    uint4 p;
    p.x = f2bf(a.x) | (f2bf(a.y) << 16);
    p.y = f2bf(a.z) | (f2bf(a.w) << 16);
    p.z = f2bf(b.x) | (f2bf(b.y) << 16);
    p.w = f2bf(b.z) | (f2bf(b.w) << 16);
    reinterpret_cast<uint4*>(out)[t] = p;
}

// ---- Phase A: partition edges into 256 dst-range buckets. ----
__global__ __launch_bounds__(256) void bucket_kernel(
        const int* __restrict__ src, const int* __restrict__ dst, int E,
        unsigned* __restrict__ bucketbuf, int* __restrict__ cursor) {
    __shared__ int h[NBUCKET];
    __shared__ int base[NBUCKET];
    int tid = threadIdx.x;
    int chunk0 = blockIdx.x * (256 * EPT);
    h[tid] = 0;
    __syncthreads();
    int myb[EPT];
    unsigned myrec[EPT];
#pragma unroll
    for (int i = 0; i < EPT; ++i) {
        int e = chunk0 + tid + i * 256;
        if (e < E) {
            int d = dst[e];
            int s = src[e];
            int b = d / NB2;            // constexpr divisor -> magic mul
            myb[i] = b;
            myrec[i] = ((unsigned)(d - b * NB2) << 17) | (unsigned)s;
            atomicAdd(&h[b], 1);
        } else {
            myb[i] = -1;
        }
    }
    __syncthreads();
    base[tid] = atomicAdd(&cursor[tid], h[tid]);
    h[tid] = 0;
    __syncthreads();
#pragma unroll
    for (int i = 0; i < EPT; ++i) {
        int b = myb[i];
        if (b < 0) continue;
        int pos = base[b] + atomicAdd(&h[b], 1);
        if (pos < BSTRIDE) bucketbuf[(size_t)b * BSTRIDE + pos] = myrec[i];
    }
}

// ---- Phase B: one block per bucket -> LDS CSR slice -> sequential store. ----
__global__ __launch_bounds__(256) void csr_build_kernel(
        const unsigned* __restrict__ bucketbuf,
        const int* __restrict__ cursor,
        int* __restrict__ rowptr,
        int* __restrict__ adj) {
    __shared__ int csr[BSTRIDE];   // 32 KB
    __shared__ int cnt[512];
    __shared__ int off[512];
    __shared__ int bscan[NBUCKET];
    int b = blockIdx.x;
    int tid = threadIdx.x;
    bscan[tid] = cursor[tid];
    int mycnt = cursor[b];
    if (mycnt > BSTRIDE) mycnt = BSTRIDE;
    blelloch_excl<NBUCKET>(bscan);
    int base = bscan[b];

    const unsigned* buf = bucketbuf + (size_t)b * BSTRIDE;
    cnt[tid] = 0;
    cnt[tid + 256] = 0;
    __syncthreads();
    for (int i = tid; i < mycnt; i += 256)
        atomicAdd(&cnt[buf[i] >> 17], 1);
    __syncthreads();
    off[tid] = cnt[tid];
    off[tid + 256] = cnt[tid + 256];
    blelloch_excl<512>(off);

    int nodes0 = b * NB2;
    int nn2 = GIN_N + 1 - nodes0;
    if (nn2 > NB2) nn2 = NB2;
    for (int l = tid; l < nn2; l += 256) rowptr[nodes0 + l] = base + off[l];
    __syncthreads();  // off reads done before scatter mutates it

    for (int i = tid; i < mycnt; i += 256) {
        unsigned r = buf[i];
        int pos = atomicAdd(&off[r >> 17], 1);
        csr[pos] = (int)(r & 0x1FFFFu);
    }
    __syncthreads();
    for (int i = tid; i < mycnt; i += 256) adj[base + i] = csr[i];
}

// ---- FUSED gather + MLP for layers 1-2.
// Phase 1: TPN=K/8 threads/node gather bf16 neighbor rows (fp32 accumulate),
// add self term, stage (x+agg) in padded LDS tile (STR=K+4 -> phase-2 reads
// are <=2-way bank-aliased = free).
// Phase 2: TP2=256/NODES threads/node run the MLP from the tile with W,b in
// LDS; bf16 output row (stride 64). ----
template <int K, bool XF32>
__global__ __launch_bounds__(256) void fused_gather_mlp_kernel(
        const float* __restrict__ xf,   // fp32 self rows (XF32) or null
        const bfu* __restrict__ xb,     // bf16 table: gather source (+self if !XF32)
        const int* __restrict__ rowptr,
        const int* __restrict__ adj,
        const float* __restrict__ W,    // K x 64
        const float* __restrict__ b,    // 64
        bfu* __restrict__ out) {        // bf16, row stride 64
    constexpr int M = 64;
    constexpr int TPN = K / 8;          // phase-1 threads per node
    constexpr int NODES = 256 / TPN;    // nodes per block
    constexpr int TP2 = 256 / NODES;    // phase-2 threads per node
    constexpr int MT = M / TP2;
    constexpr int STR = K + 4;          // padded tile row stride (x4 floats)

    __shared__ float Ws[K * M];
    __shared__ float bs[M];
    __shared__ float tile[NODES * STR];

    for (int i = threadIdx.x; i < K * M; i += 256) Ws[i] = W[i];
    if (threadIdx.x < M) bs[threadIdx.x] = b[threadIdx.x];

    int node0 = blockIdx.x * NODES;
    int tid = threadIdx.x;

    // ---- Phase 1: gather + self into tile ----
    {
        int l = tid / TPN;
        int j = tid % TPN;
        int n = node0 + l;
        if (n < GIN_N) {
            int start = rowptr[n];
            int d = rowptr[n + 1] - start;
            const int* row = adj + start;
            const uint4* f = reinterpret_cast<const uint4*>(xb);
            float acc[8];
            // self term
            if (XF32) {
                const float4* xv = reinterpret_cast<const float4*>(xf);
                float4 a = xv[(size_t)n * (K / 4) + 2 * j];
                float4 c = xv[(size_t)n * (K / 4) + 2 * j + 1];
                acc[0] = a.x; acc[1] = a.y; acc[2] = a.z; acc[3] = a.w;
                acc[4] = c.x; acc[5] = c.y; acc[6] = c.z; acc[7] = c.w;
            } else {
                uint4 u = f[(size_t)n * TPN + j];
                acc[0] = bf_lo(u.x); acc[1] = bf_hi(u.x);
                acc[2] = bf_lo(u.y); acc[3] = bf_hi(u.y);
                acc[4] = bf_lo(u.z); acc[5] = bf_hi(u.z);
                acc[6] = bf_lo(u.w); acc[7] = bf_hi(u.w);
            }
            int k = 0;
            for (; k + 4 <= d; k += 4) {
                int r0 = row[k], r1 = row[k + 1], r2 = row[k + 2], r3 = row[k + 3];
                uint4 v0 = f[(size_t)r0 * TPN + j];
                uint4 v1 = f[(size_t)r1 * TPN + j];
                uint4 v2 = f[(size_t)r2 * TPN + j];
                uint4 v3 = f[(size_t)r3 * TPN + j];
                acc[0] += bf_lo(v0.x) + bf_lo(v1.x) + bf_lo(v2.x) + bf_lo(v3.x);
                acc[1] += bf_hi(v0.x) + bf_hi(v1.x) + bf_hi(v2.x) + bf_hi(v3.x);
                acc[2] += bf_lo(v0.y) + bf_lo(v1.y) + bf_lo(v2.y) + bf_lo(v3.y);
                acc[3] += bf_hi(v0.y) + bf_hi(v1.y) + bf_hi(v2.y) + bf_hi(v3.y);
                acc[4] += bf_lo(v0.z) + bf_lo(v1.z) + bf_lo(v2.z) + bf_lo(v3.z);
                acc[5] += bf_hi(v0.z) + bf_hi(v1.z) + bf_hi(v2.z) + bf_hi(v3.z);
                acc[6] += bf_lo(v0.w) + bf_lo(v1.w) + bf_lo(v2.w) + bf_lo(v3.w);
                acc[7] += bf_hi(v0.w) + bf_hi(v1.w) + bf_hi(v2.w) + bf_hi(v3.w);
            }
            for (; k < d; ++k) {
                uint4 v = f[(size_t)row[k] * TPN + j];
                acc[0] += bf_lo(v.x); acc[1] += bf_hi(v.x);
                acc[2] += bf_lo(v.y); acc[3] += bf_hi(v.y);
                acc[4] += bf_lo(v.z); acc[5] += bf_hi(v.z);
                acc[6] += bf_lo(v.w); acc[7] += bf_hi(v.w);
            }
            float* tp = &tile[l * STR + j * 8];
#pragma unroll
            for (int q = 0; q < 8; ++q) tp[q] = acc[q];
        }
    }
    __syncthreads();

    // ---- Phase 2: MLP from tile ----
    {
        int l = tid / TP2;
        int sub = tid % TP2;
        int n = node0 + l;
        if (n >= GIN_N) return;
        float acc[MT];
#pragma unroll
        for (int jj = 0; jj < MT; ++jj) acc[jj] = bs[sub * MT + jj];
        const float* tp = &tile[l * STR];
#pragma unroll
        for (int k = 0; k < K; ++k) {
            float v = tp[k];
            const float* wr = &Ws[k * M + sub * MT];
#pragma unroll
            for (int jj = 0; jj < MT; ++jj)
                acc[jj] = fmaf(v, wr[jj], acc[jj]);
        }
        bfu* o = out + (size_t)n * M + sub * MT;
#pragma unroll
        for (int jj = 0; jj < MT; jj += 2) {
            float r0 = fmaxf(acc[jj], 0.0f);
            float r1 = fmaxf(acc[jj + 1], 0.0f);
            unsigned p = f2bf(r0) | (f2bf(r1) << 16);
            *reinterpret_cast<unsigned*>(o + jj) = p;
        }
    }
}

// ---- Layer-3 t = h2 @ W3 (bf16 in, bf16 out padded to 16 halves). ----
__global__ __launch_bounds__(256) void mlp3_kernel(
        const bfu* __restrict__ xb,     // h2, bf16, stride 64
        const float* __restrict__ W,    // 64 x 10
        bfu* __restrict__ t16) {        // bf16, stride 16 (10 used)
    constexpr int K = 64, M = 10, TPN = 2, MT = 5;
    __shared__ float Ws[K * M];
    for (int i = threadIdx.x; i < K * M; i += 256) Ws[i] = W[i];
    __syncthreads();
    int t = blockIdx.x * blockDim.x + threadIdx.x;
    int n = t / TPN;
    int sub = t % TPN;
    if (n >= GIN_N) return;
    float acc[MT] = {0, 0, 0, 0, 0};
#pragma unroll
    for (int kc = 0; kc < K / 8; ++kc) {
        uint4 u = reinterpret_cast<const uint4*>(xb)[(size_t)n * (K / 8) + kc];
        float v[8] = {bf_lo(u.x), bf_hi(u.x), bf_lo(u.y), bf_hi(u.y),
                      bf_lo(u.z), bf_hi(u.z), bf_lo(u.w), bf_hi(u.w)};
#pragma unroll
        for (int kk = 0; kk < 8; ++kk) {
            const float* wr = &Ws[(kc * 8 + kk) * M + sub * MT];
#pragma unroll
            for (int jj = 0; jj < MT; ++jj)
                acc[jj] = fmaf(v[kk], wr[jj], acc[jj]);
        }
    }
    bfu* o = t16 + (size_t)n * 16 + sub * MT;
#pragma unroll
    for (int jj = 0; jj < MT; ++jj) o[jj] = (bfu)f2bf(acc[jj]);
}

// ---- Final aggregation over bf16 t rows (16 halves = 8 uints):
// out = t + A t + b3. 8 threads/node, active j<5, 2 dims each. ----
__global__ void gather_final_kernel(const unsigned* __restrict__ t8,
                                    const int* __restrict__ rowptr,
                                    const int* __restrict__ adj,
                                    const float* __restrict__ b3,
                                    float* __restrict__ out) {
    int t = blockIdx.x * blockDim.x + threadIdx.x;
    int n = t >> 3;
    int j = t & 7;
    if (n >= GIN_N || j >= 5) return;
    int start = rowptr[n];
    int d = rowptr[n + 1] - start;
    const int* row = adj + start;
    unsigned sv = t8[(size_t)n * 8 + j];
    float a0 = bf_lo(sv), a1 = bf_hi(sv);
    int k = 0;
    for (; k + 4 <= d; k += 4) {
        int r0 = row[k], r1 = row[k + 1], r2 = row[k + 2], r3 = row[k + 3];
        unsigned v0 = t8[(size_t)r0 * 8 + j];
        unsigned v1 = t8[(size_t)r1 * 8 + j];
        unsigned v2 = t8[(size_t)r2 * 8 + j];
        unsigned v3 = t8[(size_t)r3 * 8 + j];
        a0 += bf_lo(v0) + bf_lo(v1) + bf_lo(v2) + bf_lo(v3);
        a1 += bf_hi(v0) + bf_hi(v1) + bf_hi(v2) + bf_hi(v3);
    }
    for (; k < d; ++k) {
        unsigned v = t8[(size_t)row[k] * 8 + j];
        a0 += bf_lo(v); a1 += bf_hi(v);
    }
    out[(size_t)n * 10 + 2 * j] = a0 + b3[2 * j];
    out[(size_t)n * 10 + 2 * j + 1] = a1 + b3[2 * j + 1];
}

extern "C" void kernel_launch(void* const* d_in, const int* in_sizes, int n_in,
                              void* d_out, int out_size, void* d_ws, size_t ws_size,
                              hipStream_t stream) {
    const float* x  = (const float*)d_in[0];
    const int*   ei = (const int*)d_in[1];
    const float* W1 = (const float*)d_in[2];
    const float* b1 = (const float*)d_in[3];
    const float* W2 = (const float*)d_in[4];
    const float* b2 = (const float*)d_in[5];
    const float* W3 = (const float*)d_in[6];
    const float* b3 = (const float*)d_in[7];
    float* out = (float*)d_out;

    const int N = GIN_N;
    const int E = in_sizes[1] / 2;   // edge_index is [2, E]
    const int* src = ei;
    const int* dst = ei + E;

    // Workspace layout (segments 16B-aligned):
    //   H1      bf16 N*64            12.8 MB
    //   H2      bf16 N*64            12.8 MB
    //   Xb      bf16 N*32             6.4 MB
    //   Tb      bf16 N*16             3.2 MB
    //   rowptr  int  N+8              0.4 MB
    //   cursor  int  256
    //   adj     int  E                6.4 MB  (packed CSR)
    //   bkt     uint 256*BSTRIDE      8.4 MB          total ~50 MB
    bfu* H1 = (bfu*)d_ws;
    bfu* H2 = H1 + (size_t)N * 64;
    bfu* Xb = H2 + (size_t)N * 64;
    bfu* Tb = Xb + (size_t)N * 32;
    int* rowptr = (int*)(Tb + (size_t)N * 16);
    int* cursor = rowptr + (N + 8);
    int* adj = cursor + 256;
    unsigned* bucketbuf = (unsigned*)(adj + (size_t)E);

    const int BLK = 256;

    // ---- Adjacency build: bucket -> LDS-staged CSR ----
    hipMemsetAsync(cursor, 0, 256 * sizeof(int), stream);
    {
        int chunk = BLK * EPT;
        bucket_kernel<<<(E + chunk - 1) / chunk, BLK, 0, stream>>>(
            src, dst, E, bucketbuf, cursor);
        csr_build_kernel<<<NBUCKET, BLK, 0, stream>>>(
            bucketbuf, cursor, rowptr, adj);
    }
    f2bf_kernel<<<(N * 32 / 8 + BLK - 1) / BLK, BLK, 0, stream>>>(x, Xb, N * 32 / 8);

    // ---- Layer 1 fused: d=32 -> 64, ReLU (gather bf16 Xb, self fp32 x) ----
    fused_gather_mlp_kernel<32, true><<<(N + 63) / 64, BLK, 0, stream>>>(
        x, Xb, rowptr, adj, W1, b1, H1);

    // ---- Layer 2 fused: d=64 -> 64, ReLU ----
    fused_gather_mlp_kernel<64, false><<<(N + 31) / 32, BLK, 0, stream>>>(
        nullptr, H1, rowptr, adj, W2, b2, H2);

    // ---- Layer 3: t = h2 @ W3 (bf16, padded 16), out = t + A t + b3 ----
    mlp3_kernel<<<(N * 2 + BLK - 1) / BLK, BLK, 0, stream>>>(H2, W3, Tb);
    gather_final_kernel<<<(N * 8 + BLK - 1) / BLK, BLK, 0, stream>>>(
        (const unsigned*)Tb, rowptr, adj, b3, out);
}